// Round 7
// baseline (332.198 us; speedup 1.0000x reference)
//
#include <hip/hip_runtime.h>
#include <cmath>

#define LN_EPS 1e-5f

typedef float  f32x4  __attribute__((ext_vector_type(4)));
typedef short  short8 __attribute__((ext_vector_type(8)));
typedef unsigned int uint4v __attribute__((ext_vector_type(4)));

// ws layout (bytes):
//   w1f  : 5*8*64*16 = 40960   (uint4 frags, B-operand layout, bf16)
//   w2f  : 4*8*64*16 = 32768
//   emb16: NUM_TYPES*128*2     (row-major bf16)
//   tps  : 5 floats (uniform temporal-LN closed-form sums)
#define W1F_U4 2560   // 5*8*64
#define W2F_U4 2048   // 4*8*64

__device__ __forceinline__ unsigned short f32_bf16_rne(float f) {
    union { float f; unsigned u; } v; v.f = f;
    unsigned r = v.u + 0x7FFFu + ((v.u >> 16) & 1u);
    return (unsigned short)(r >> 16);
}

// packed f32->bf16 (RNE), 1 VALU op for 2 elements
__device__ __forceinline__ unsigned cvt_pk_bf16(float lo, float hi) {
    unsigned r;
    asm("v_cvt_pk_bf16_f32 %0, %1, %2" : "=v"(r) : "v"(lo), "v"(hi));
    return r;
}

// exact-erf GELU via Abramowitz&Stegun 7.1.26 (|err| <= 1.5e-7)
__device__ __forceinline__ float gelu_f(float x) {
    float ax = fabsf(x);
    float a  = ax * 0.70710678118654752f;          // |x|/sqrt(2)
    float t  = __builtin_amdgcn_rcpf(fmaf(0.3275911f, a, 1.0f));
    float p  = t * fmaf(t, fmaf(t, fmaf(t, fmaf(t, 1.061405429f, -1.453152027f),
                                        1.421413741f), -0.284496736f), 0.254829592f);
    float e  = __builtin_amdgcn_exp2f(-1.44269504089f * a * a);
    float E  = fmaf(-p, e, 1.0f);                  // erf(|x|/sqrt2)
    return 0.5f * fmaf(ax, E, x);                  // 0.5*(x + |x|*erf)
}

// DPP row-rotate add: sum over the 16-lane DPP row, all lanes get the result.
template<int C>
__device__ __forceinline__ float dpp_radd(float x) {
    int t = __builtin_amdgcn_update_dpp(0, __builtin_bit_cast(int, x), C, 0xF, 0xF, true);
    return x + __builtin_bit_cast(float, t);
}
__device__ __forceinline__ float red16(float x) {
    x = dpp_radd<0x128>(x);   // row_ror:8
    x = dpp_radd<0x124>(x);   // row_ror:4
    x = dpp_radd<0x122>(x);   // row_ror:2
    x = dpp_radd<0x121>(x);   // row_ror:1
    return x;
}

// -------- prep: swizzle w1/w2 into MFMA B-fragment layout (bf16), convert emb
//          to bf16 rows, compute temporal-LN sums. Re-run every call.
__global__ void prep_kernel(const float* __restrict__ w1, const float* __restrict__ w2,
                            const float* __restrict__ emb,
                            const float* __restrict__ tp_w, const float* __restrict__ tp_b,
                            unsigned* __restrict__ ws, int emb_pairs) {
    const int tid = blockIdx.x * 256 + threadIdx.x;   // 8192 threads
    uint4v* w1f = (uint4v*)ws;
    uint4v* w2f = w1f + W1F_U4;
    unsigned* emb16 = (unsigned*)(w2f + W2F_U4);

    for (int i = tid; i < W1F_U4; i += 8192) {        // frag(kt,nt,lane): B[k][n]
        const int lane = i & 63, nt = (i >> 6) & 7, kt = i >> 9;
        const int k0 = kt * 32 + (lane >> 4) * 8, n = nt * 16 + (lane & 15);
        uint4v r;
        #pragma unroll
        for (int j2 = 0; j2 < 4; ++j2) {
            unsigned lo = f32_bf16_rne(w1[(k0 + 2 * j2) * 128 + n]);
            unsigned hi = f32_bf16_rne(w1[(k0 + 2 * j2 + 1) * 128 + n]);
            r[j2] = lo | (hi << 16);
        }
        w1f[i] = r;
    }
    for (int i = tid; i < W2F_U4; i += 8192) {
        const int lane = i & 63, nt = (i >> 6) & 7, kt = i >> 9;
        const int k0 = kt * 32 + (lane >> 4) * 8, n = nt * 16 + (lane & 15);
        uint4v r;
        #pragma unroll
        for (int j2 = 0; j2 < 4; ++j2) {
            unsigned lo = f32_bf16_rne(w2[(k0 + 2 * j2) * 128 + n]);
            unsigned hi = f32_bf16_rne(w2[(k0 + 2 * j2 + 1) * 128 + n]);
            r[j2] = lo | (hi << 16);
        }
        w2f[i] = r;
    }
    for (int i = tid; i < emb_pairs; i += 8192) {
        unsigned lo = f32_bf16_rne(emb[2 * i]);
        unsigned hi = f32_bf16_rne(emb[2 * i + 1]);
        emb16[i] = lo | (hi << 16);
    }
    if (tid == 0) {                                   // uniform temporal-LN sums
        float Sw = 0.f, Sb = 0.f, Sww = 0.f, Swb = 0.f, Sbb = 0.f;
        for (int j = 0; j < 32; ++j) {
            const float ww = tp_w[j], bb = tp_b[j];
            Sw += ww; Sb += bb; Sww += ww * ww; Swb += ww * bb; Sbb += bb * bb;
        }
        float* tps = (float*)(emb16 + emb_pairs);
        tps[0] = Sw; tps[1] = Sb; tps[2] = Sww; tps[3] = Swb; tps[4] = Sbb;
    }
}

// -------- main: one block per batch row. 4 waves loop over 32-row SUPER-tiles
//          (mt=2 x 16 rows): st = w, w+4, ... Balanced, no early-exit waves.
//          Pool in registers, cross-wave combine in LDS -> ONE plain store per
//          row (zero atomics).
//
// REGISTER DISCIPLINE (rounds 2-5 spill saga): (256,2) = 128 arch + 128 acc is
// the ONLY no-spill regime for this structure (FETCH 11 MB vs 540-650 MB at
// (256,3)/(256,4)). Do NOT tighten launch bounds. Coefficients live in LDS.
//
// PIPELINE (round 7): waves are independent (no cross-wave a2 sharing), and
// per-wave LDS ops execute in order in the DS pipe, so a2 write->read only
// needs a COMPILER ordering fence (empty asm memory clobber) -- NOT
// s_waitcnt lgkmcnt(0) + sched_barrier(0), which drained all LDS and pinned
// the schedule, serializing every phase. The middle phases are split per-mt:
//   epi1(0) | fence | {GEMM2(0) || epi1(1)} | fence | {GEMM2(1) || epi2(0)} | epi2(1)
// so each GEMM2's w2f L2-load latency + MFMA hides under an epilogue's VALU.
__global__ __launch_bounds__(256, 2) void encoder_mfma(
    const int*   __restrict__ tids,  const float* __restrict__ dates,
    const int*   __restrict__ lengths,
    const float* __restrict__ tp_w,  const float* __restrict__ tp_b,
    const float* __restrict__ tp_lnw,const float* __restrict__ tp_lnb,
    const float* __restrict__ b1,    const float* __restrict__ ln1w, const float* __restrict__ ln1b,
    const float* __restrict__ b2,    const float* __restrict__ ln2w, const float* __restrict__ ln2b,
    const unsigned* __restrict__ ws, float* __restrict__ out, int L, int emb_pairs)
{
    // per-wave C->A transpose scratch: [wave][mt][kt2][row64 (XOR-swizzled)][j]
    __shared__ __align__(16) unsigned short a2[4][2][4][64][8];   // 32 KB
    __shared__ float poolbuf[4][128];                             // 2 KB
    // loop-invariant coefficients, packed f32x4 per column (16B stride ->
    // worst-case 2-way bank aliasing = free):
    __shared__ __align__(16) f32x4 tcoef[32];    // {tp_w, tp_b, tp_lnw, tp_lnb}
    __shared__ __align__(16) f32x4 ecoef1[128];  // {b1, ln1w, ln1b, -}
    __shared__ __align__(16) f32x4 ecoef2[128];  // {b2, ln2w, ln2b, -}

    const int b   = blockIdx.x;
    const int tid = threadIdx.x;
    const int lane = tid & 63, w = tid >> 6;
    const int c = lane & 15, g = lane >> 4;
    const int len = min(max(lengths[b], 0), L);
    const int nst = (len + 31) >> 5;                  // 32-row super-tiles

    const uint4v* w1f = (const uint4v*)ws;
    const uint4v* w2f = w1f + W1F_U4;
    const unsigned short* emb16 = (const unsigned short*)(w2f + W2F_U4);
    const float* tps = (const float*)(emb16 + emb_pairs * 2);

    // fill coefficient LDS (block prologue, one barrier)
    if (tid < 32)  tcoef[tid]  = (f32x4){tp_w[tid], tp_b[tid], tp_lnw[tid], tp_lnb[tid]};
    if (tid < 128) {
        ecoef1[tid] = (f32x4){b1[tid], ln1w[tid], ln1b[tid], 0.f};
        ecoef2[tid] = (f32x4){b2[tid], ln2w[tid], ln2b[tid], 0.f};
    }
    __syncthreads();

    const float Sw = tps[0], Sb = tps[1], Sww = tps[2], Swb = tps[3], Sbb = tps[4];

    float pool[8];
    #pragma unroll
    for (int nt = 0; nt < 8; ++nt) pool[nt] = 0.f;
    const int srl = lane ^ ((lane >> 3) & 3);          // swizzled GEMM2 read row

    // epilogue 1 for one 16-row m-tile: +b1, LN1 (DPP reduce), GELU -> a2[mt]
    auto epi1 = [&](f32x4 (&am)[8], int mt) {
        f32x4 e1[8];
        #pragma unroll
        for (int nt = 0; nt < 8; ++nt) e1[nt] = ecoef1[nt * 16 + c];
        #pragma unroll
        for (int r = 0; r < 4; ++r) {
            float v[8], s = 0.f, q = 0.f;
            #pragma unroll
            for (int nt = 0; nt < 8; ++nt) {
                v[nt] = am[nt][r] + e1[nt][0];
                s += v[nt]; q = fmaf(v[nt], v[nt], q);
            }
            s = red16(s); q = red16(q);
            const float mean = s * (1.f / 128.f);
            const float var  = fmaxf(q * (1.f / 128.f) - mean * mean, 0.f);
            const float rstd = rsqrtf(var + LN_EPS);
            const int mrow = 4 * g + r;
            #pragma unroll
            for (int n2 = 0; n2 < 4; ++n2) {
                const float y0 = gelu_f(fmaf((v[2*n2]   - mean) * rstd, e1[2*n2][1],   e1[2*n2][2]));
                const float y1 = gelu_f(fmaf((v[2*n2+1] - mean) * rstd, e1[2*n2+1][1], e1[2*n2+1][2]));
                const unsigned pk = cvt_pk_bf16(y0, y1);
                {
                    const int kcol  = (2*n2) * 16 + c;
                    const int row64 = ((kcol >> 3) & 3) * 16 + mrow;
                    const int srow  = row64 ^ ((row64 >> 3) & 3);
                    a2[w][mt][kcol >> 5][srow][kcol & 7] = (unsigned short)(pk & 0xffffu);
                }
                {
                    const int kcol  = (2*n2+1) * 16 + c;
                    const int row64 = ((kcol >> 3) & 3) * 16 + mrow;
                    const int srow  = row64 ^ ((row64 >> 3) & 3);
                    a2[w][mt][kcol >> 5][srow][kcol & 7] = (unsigned short)(pk >> 16);
                }
            }
        }
    };

    // GEMM2 for one m-tile: a2[mt] @ w2 -> c2
    auto gemm2 = [&](f32x4 (&c2)[8], int mt) {
        #pragma unroll
        for (int nt = 0; nt < 8; ++nt) c2[nt] = (f32x4){0.f, 0.f, 0.f, 0.f};
        __builtin_amdgcn_s_setprio(1);
        #pragma unroll
        for (int kt2 = 0; kt2 < 4; ++kt2) {
            short8 af;
            __builtin_memcpy(&af, &a2[w][mt][kt2][srl][0], 16);
            #pragma unroll
            for (int nt = 0; nt < 8; ++nt) {
                const short8 bf = ((const short8*)w2f)[(kt2 * 8 + nt) * 64 + lane];
                c2[nt] = __builtin_amdgcn_mfma_f32_16x16x32_bf16(af, bf, c2[nt], 0, 0, 0);
            }
        }
        __builtin_amdgcn_s_setprio(0);
    };

    // epilogue 2 for one m-tile: +b2, LN2, mask, pool
    auto epi2 = [&](f32x4 (&c2)[8], int rowbase) {
        f32x4 e2[8];
        #pragma unroll
        for (int nt = 0; nt < 8; ++nt) e2[nt] = ecoef2[nt * 16 + c];
        #pragma unroll
        for (int r = 0; r < 4; ++r) {
            float v[8], s = 0.f, q = 0.f;
            #pragma unroll
            for (int nt = 0; nt < 8; ++nt) {
                v[nt] = c2[nt][r] + e2[nt][0];
                s += v[nt]; q = fmaf(v[nt], v[nt], q);
            }
            s = red16(s); q = red16(q);
            const float mean = s * (1.f / 128.f);
            const float var  = fmaxf(q * (1.f / 128.f) - mean * mean, 0.f);
            const float rstd = rsqrtf(var + LN_EPS);
            const float msk = ((rowbase + 4 * g + r) < len) ? 1.f : 0.f;
            #pragma unroll
            for (int nt = 0; nt < 8; ++nt) {
                const float y = fmaf((v[nt] - mean) * rstd, e2[nt][1], e2[nt][2]);
                pool[nt] = fmaf(y, msk, pool[nt]);
            }
        }
    };

    for (int st = w; st < nst; st += 4) {
        const int R0 = st << 5;
        int   id[2]; float dn[2];
        #pragma unroll
        for (int mt = 0; mt < 2; ++mt) {
            const int p  = R0 + mt * 16 + c;
            const int pc = min(p, L - 1);
            id[mt]  = tids[b * L + pc];
            dn[mt]  = dates[b * L + pc] * (1.f / 1825.f);
        }
        const bool amt1 = (R0 + 16) < len;             // wave-uniform

        // temporal A-frags (row = c, k-chunk = g*8..g*8+7); coeffs from LDS
        short8 tfrag[2];
        #pragma unroll
        for (int mt = 0; mt < 2; ++mt) {
            const float d  = dn[mt];
            const float tm = fmaf(d, Sw, Sb) * (1.f / 32.f);
            float tv = fmaf(d * d, Sww, fmaf(2.f * d, Swb, Sbb)) * (1.f / 32.f) - tm * tm;
            const float trs = rsqrtf(fmaxf(tv, 0.f) + LN_EPS);
            const int j0 = g * 8;
            uint4v r;
            #pragma unroll
            for (int j2 = 0; j2 < 4; ++j2) {
                const f32x4 t0 = tcoef[j0 + 2*j2];
                const f32x4 t1 = tcoef[j0 + 2*j2 + 1];
                const float y0 = fmaf((fmaf(d, t0[0], t0[1]) - tm) * trs, t0[2], t0[3]);
                const float y1 = fmaf((fmaf(d, t1[0], t1[1]) - tm) * trs, t1[2], t1[3]);
                r[j2] = cvt_pk_bf16(gelu_f(y0), gelu_f(y1));
            }
            union { uint4v u; short8 s; } cv; cv.u = r;
            tfrag[mt] = cv.s;
        }

        // ---------------- GEMM1: [2mt x 16][K=160] @ w1 ----------------
        f32x4 acc[2][8];
        #pragma unroll
        for (int mt = 0; mt < 2; ++mt)
            #pragma unroll
            for (int nt = 0; nt < 8; ++nt) acc[mt][nt] = (f32x4){0.f, 0.f, 0.f, 0.f};
        __builtin_amdgcn_s_setprio(1);
        #pragma unroll
        for (int kt = 0; kt < 5; ++kt) {
            short8 af[2];
            if (kt < 4) {
                #pragma unroll
                for (int mt = 0; mt < 2; ++mt)
                    af[mt] = *(const short8*)(emb16 + id[mt] * 128 + kt * 32 + g * 8);
            } else {
                #pragma unroll
                for (int mt = 0; mt < 2; ++mt) af[mt] = tfrag[mt];
            }
            #pragma unroll
            for (int nt = 0; nt < 8; ++nt) {
                const short8 bf = ((const short8*)w1f)[(kt * 8 + nt) * 64 + lane];
                #pragma unroll
                for (int mt = 0; mt < 2; ++mt)
                    acc[mt][nt] = __builtin_amdgcn_mfma_f32_16x16x32_bf16(af[mt], bf, acc[mt][nt], 0, 0, 0);
            }
        }
        __builtin_amdgcn_s_setprio(0);

        // -------- 2-stage per-mt pipeline --------
        f32x4 acc2[2][8];

        epi1(acc[0], 0);
        asm volatile("" ::: "memory");                 // order a2[0] W->R (DS pipe is
                                                       // per-wave in-order; no drain)
        gemm2(acc2[0], 0);                             // || with epi1(1): MFMA+loads
        if (amt1) epi1(acc[1], 1);                     //    overlap epilogue VALU
        asm volatile("" ::: "memory");                 // order a2[1] W->R

        if (amt1) gemm2(acc2[1], 1);                   // || with epi2(0)
        epi2(acc2[0], R0);
        if (amt1) epi2(acc2[1], R0 + 16);
    }

    // wave-level pool reduce (over g groups), then cross-wave combine in LDS
    #pragma unroll
    for (int nt = 0; nt < 8; ++nt) {
        float tv = pool[nt];
        tv += __shfl_xor(tv, 16);
        tv += __shfl_xor(tv, 32);
        pool[nt] = tv;
    }
    if (g == 0) {
        #pragma unroll
        for (int nt = 0; nt < 8; ++nt) poolbuf[w][nt * 16 + c] = pool[nt];
    }
    __syncthreads();
    if (tid < 128) {
        const float s = poolbuf[0][tid] + poolbuf[1][tid] + poolbuf[2][tid] + poolbuf[3][tid];
        out[b * 128 + tid] = (len > 0) ? s / (float)len : 0.f;
    }
}

extern "C" void kernel_launch(void* const* d_in, const int* in_sizes, int n_in,
                              void* d_out, int out_size, void* d_ws, size_t ws_size,
                              hipStream_t stream) {
    const int*   tids    = (const int*)  d_in[0];
    const float* dates   = (const float*)d_in[1];
    const int*   lengths = (const int*)  d_in[2];
    const float* emb     = (const float*)d_in[3];
    const float* tp_w    = (const float*)d_in[4];
    const float* tp_b    = (const float*)d_in[5];
    const float* tp_lnw  = (const float*)d_in[6];
    const float* tp_lnb  = (const float*)d_in[7];
    const float* w1      = (const float*)d_in[8];
    const float* b1      = (const float*)d_in[9];
    const float* ln1w    = (const float*)d_in[10];
    const float* ln1b    = (const float*)d_in[11];
    const float* w2      = (const float*)d_in[12];
    const float* b2      = (const float*)d_in[13];
    const float* ln2w    = (const float*)d_in[14];
    const float* ln2b    = (const float*)d_in[15];
    float* out = (float*)d_out;

    const int B = in_sizes[2];
    const int L = in_sizes[0] / B;
    const int emb_pairs = in_sizes[3] / 2;

    hipLaunchKernelGGL(prep_kernel, dim3(32), dim3(256), 0, stream,
                       w1, w2, emb, tp_w, tp_b, (unsigned*)d_ws, emb_pairs);
    hipLaunchKernelGGL(encoder_mfma, dim3(B), dim3(256), 0, stream,
                       tids, dates, lengths, tp_w, tp_b, tp_lnw, tp_lnb,
                       b1, ln1w, ln1b, b2, ln2w, ln2b,
                       (const unsigned*)d_ws, out, L, emb_pairs);
}

// Round 8
// 239.036 us; speedup vs baseline: 1.3897x; 1.3897x over previous
//
#include <hip/hip_runtime.h>
#include <cmath>

#define LN_EPS 1e-5f

typedef float  f32x4  __attribute__((ext_vector_type(4)));
typedef short  short8 __attribute__((ext_vector_type(8)));
typedef unsigned int uint4v __attribute__((ext_vector_type(4)));

// ws layout (bytes):
//   w1f  : 5*8*64*16 = 40960   (uint4 frags, B-operand layout, bf16)
//   w2f  : 4*8*64*16 = 32768
//   emb16: NUM_TYPES*128*2     (row-major bf16)
//   tps  : 5 floats (uniform temporal-LN closed-form sums)
#define W1F_U4 2560   // 5*8*64
#define W2F_U4 2048   // 4*8*64
#define WLDS_U4 4608  // staged in LDS per block

__device__ __forceinline__ unsigned short f32_bf16_rne(float f) {
    union { float f; unsigned u; } v; v.f = f;
    unsigned r = v.u + 0x7FFFu + ((v.u >> 16) & 1u);
    return (unsigned short)(r >> 16);
}

// packed f32->bf16 (RNE), 1 VALU op for 2 elements
__device__ __forceinline__ unsigned cvt_pk_bf16(float lo, float hi) {
    unsigned r;
    asm("v_cvt_pk_bf16_f32 %0, %1, %2" : "=v"(r) : "v"(lo), "v"(hi));
    return r;
}

// exact-erf GELU via Abramowitz&Stegun 7.1.26 (|err| <= 1.5e-7)
__device__ __forceinline__ float gelu_f(float x) {
    float ax = fabsf(x);
    float a  = ax * 0.70710678118654752f;          // |x|/sqrt(2)
    float t  = __builtin_amdgcn_rcpf(fmaf(0.3275911f, a, 1.0f));
    float p  = t * fmaf(t, fmaf(t, fmaf(t, fmaf(t, 1.061405429f, -1.453152027f),
                                        1.421413741f), -0.284496736f), 0.254829592f);
    float e  = __builtin_amdgcn_exp2f(-1.44269504089f * a * a);
    float E  = fmaf(-p, e, 1.0f);                  // erf(|x|/sqrt2)
    return 0.5f * fmaf(ax, E, x);                  // 0.5*(x + |x|*erf)
}

// DPP row-rotate add: sum over the 16-lane DPP row, all lanes get the result.
template<int C>
__device__ __forceinline__ float dpp_radd(float x) {
    int t = __builtin_amdgcn_update_dpp(0, __builtin_bit_cast(int, x), C, 0xF, 0xF, true);
    return x + __builtin_bit_cast(float, t);
}
__device__ __forceinline__ float red16(float x) {
    x = dpp_radd<0x128>(x);   // row_ror:8
    x = dpp_radd<0x124>(x);   // row_ror:4
    x = dpp_radd<0x122>(x);   // row_ror:2
    x = dpp_radd<0x121>(x);   // row_ror:1
    return x;
}

// -------- prep: swizzle w1/w2 into MFMA B-fragment layout (bf16), convert emb
//          to bf16 rows, compute temporal-LN sums. Re-run every call.
__global__ void prep_kernel(const float* __restrict__ w1, const float* __restrict__ w2,
                            const float* __restrict__ emb,
                            const float* __restrict__ tp_w, const float* __restrict__ tp_b,
                            unsigned* __restrict__ ws, int emb_pairs) {
    const int tid = blockIdx.x * 256 + threadIdx.x;   // 8192 threads
    uint4v* w1f = (uint4v*)ws;
    uint4v* w2f = w1f + W1F_U4;
    unsigned* emb16 = (unsigned*)(w2f + W2F_U4);

    for (int i = tid; i < W1F_U4; i += 8192) {        // frag(kt,nt,lane): B[k][n]
        const int lane = i & 63, nt = (i >> 6) & 7, kt = i >> 9;
        const int k0 = kt * 32 + (lane >> 4) * 8, n = nt * 16 + (lane & 15);
        uint4v r;
        #pragma unroll
        for (int j2 = 0; j2 < 4; ++j2) {
            unsigned lo = f32_bf16_rne(w1[(k0 + 2 * j2) * 128 + n]);
            unsigned hi = f32_bf16_rne(w1[(k0 + 2 * j2 + 1) * 128 + n]);
            r[j2] = lo | (hi << 16);
        }
        w1f[i] = r;
    }
    for (int i = tid; i < W2F_U4; i += 8192) {
        const int lane = i & 63, nt = (i >> 6) & 7, kt = i >> 9;
        const int k0 = kt * 32 + (lane >> 4) * 8, n = nt * 16 + (lane & 15);
        uint4v r;
        #pragma unroll
        for (int j2 = 0; j2 < 4; ++j2) {
            unsigned lo = f32_bf16_rne(w2[(k0 + 2 * j2) * 128 + n]);
            unsigned hi = f32_bf16_rne(w2[(k0 + 2 * j2 + 1) * 128 + n]);
            r[j2] = lo | (hi << 16);
        }
        w2f[i] = r;
    }
    for (int i = tid; i < emb_pairs; i += 8192) {
        unsigned lo = f32_bf16_rne(emb[2 * i]);
        unsigned hi = f32_bf16_rne(emb[2 * i + 1]);
        emb16[i] = lo | (hi << 16);
    }
    if (tid == 0) {                                   // uniform temporal-LN sums
        float Sw = 0.f, Sb = 0.f, Sww = 0.f, Swb = 0.f, Sbb = 0.f;
        for (int j = 0; j < 32; ++j) {
            const float ww = tp_w[j], bb = tp_b[j];
            Sw += ww; Sb += bb; Sww += ww * ww; Swb += ww * bb; Sbb += bb * bb;
        }
        float* tps = (float*)(emb16 + emb_pairs);
        tps[0] = Sw; tps[1] = Sb; tps[2] = Sww; tps[3] = Swb; tps[4] = Sbb;
    }
}

// -------- main: 512 threads = 8 waves; TWO batch rows per block (waves w with
//          w&1==row handle row, 4 waves per row looping 32-row super-tiles).
//          w1f+w2f (72 KB) staged in LDS once per block -> per-supertile weight
//          reads are ds_read_b128 (~12 cy) instead of L2 loads (~200+ cy),
//          removing the dominant stall in the round-6 serial chain.
//
// REGISTER DISCIPLINE (rounds 2-5,7 spill saga): 256 regs/wave (128 arch +
// 128 acc) is the only no-spill regime. Round 7 proved even extending acc
// live ranges for overlap spills (WRITE 37->137 MB). Phases stay STRICTLY
// serial per mt; acc2 and a2 are single-mt to cut pressure. Occupancy is
// reg-capped at 2 waves/SIMD regardless, so 1 block x 8 waves == 2 x 4.
__global__ __launch_bounds__(512, 2) void encoder_mfma(
    const int*   __restrict__ tids,  const float* __restrict__ dates,
    const int*   __restrict__ lengths,
    const float* __restrict__ tp_w,  const float* __restrict__ tp_b,
    const float* __restrict__ tp_lnw,const float* __restrict__ tp_lnb,
    const float* __restrict__ b1,    const float* __restrict__ ln1w, const float* __restrict__ ln1b,
    const float* __restrict__ b2,    const float* __restrict__ ln2w, const float* __restrict__ ln2b,
    const unsigned* __restrict__ ws, float* __restrict__ out,
    int B, int L, int emb_pairs)
{
    __shared__ __align__(16) uint4v wlds[WLDS_U4];                // 72 KB: w1f|w2f
    // per-wave C->A transpose scratch (single m-tile): [wave][kt2][row64][j]
    __shared__ __align__(16) unsigned short a2[8][4][64][8];      // 32 KB
    __shared__ float poolbuf[2][4][128];                          // 4 KB
    __shared__ __align__(16) f32x4 tcoef[32];    // {tp_w, tp_b, tp_lnw, tp_lnb}
    __shared__ __align__(16) f32x4 ecoef1[128];  // {b1, ln1w, ln1b, -}
    __shared__ __align__(16) f32x4 ecoef2[128];  // {b2, ln2w, ln2b, -}

    const int tid = threadIdx.x;
    const int lane = tid & 63, w = tid >> 6;          // w in 0..7
    const int c = lane & 15, g = lane >> 4;
    const int row = w & 1;
    const int b   = blockIdx.x * 2 + row;

    // ---- stage weights into LDS (4608 uint4 by 512 threads: 9 each) ----
    #pragma unroll
    for (int i = 0; i < 9; ++i)
        wlds[i * 512 + tid] = ((const uint4v*)ws)[i * 512 + tid];

    const unsigned short* emb16 = (const unsigned short*)((const uint4v*)ws + W1F_U4 + W2F_U4);
    const float* tps = (const float*)(emb16 + emb_pairs * 2);

    if (tid < 32)  tcoef[tid]  = (f32x4){tp_w[tid], tp_b[tid], tp_lnw[tid], tp_lnb[tid]};
    if (tid < 128) {
        ecoef1[tid] = (f32x4){b1[tid], ln1w[tid], ln1b[tid], 0.f};
        ecoef2[tid] = (f32x4){b2[tid], ln2w[tid], ln2b[tid], 0.f};
    }
    __syncthreads();

    const float Sw = tps[0], Sb = tps[1], Sww = tps[2], Swb = tps[3], Sbb = tps[4];

    const int len = (b < B) ? min(max(lengths[b], 0), L) : 0;
    const int nst = (len + 31) >> 5;                  // 32-row super-tiles

    float pool[8];
    #pragma unroll
    for (int nt = 0; nt < 8; ++nt) pool[nt] = 0.f;
    const int srl = lane ^ ((lane >> 3) & 3);          // swizzled GEMM2 read row

    // epilogue 1 (one 16-row m-tile): +b1, LN1 (DPP), GELU -> a2[w] (swizzled)
    auto epi1 = [&](f32x4 (&am)[8]) {
        f32x4 e1[8];
        #pragma unroll
        for (int nt = 0; nt < 8; ++nt) e1[nt] = ecoef1[nt * 16 + c];
        #pragma unroll
        for (int r = 0; r < 4; ++r) {
            float v[8], s = 0.f, q = 0.f;
            #pragma unroll
            for (int nt = 0; nt < 8; ++nt) {
                v[nt] = am[nt][r] + e1[nt][0];
                s += v[nt]; q = fmaf(v[nt], v[nt], q);
            }
            s = red16(s); q = red16(q);
            const float mean = s * (1.f / 128.f);
            const float var  = fmaxf(q * (1.f / 128.f) - mean * mean, 0.f);
            const float rstd = rsqrtf(var + LN_EPS);
            const int mrow = 4 * g + r;
            #pragma unroll
            for (int n2 = 0; n2 < 4; ++n2) {
                const float y0 = gelu_f(fmaf((v[2*n2]   - mean) * rstd, e1[2*n2][1],   e1[2*n2][2]));
                const float y1 = gelu_f(fmaf((v[2*n2+1] - mean) * rstd, e1[2*n2+1][1], e1[2*n2+1][2]));
                const unsigned pk = cvt_pk_bf16(y0, y1);
                {
                    const int kcol  = (2*n2) * 16 + c;
                    const int row64 = ((kcol >> 3) & 3) * 16 + mrow;
                    const int srow  = row64 ^ ((row64 >> 3) & 3);
                    a2[w][kcol >> 5][srow][kcol & 7] = (unsigned short)(pk & 0xffffu);
                }
                {
                    const int kcol  = (2*n2+1) * 16 + c;
                    const int row64 = ((kcol >> 3) & 3) * 16 + mrow;
                    const int srow  = row64 ^ ((row64 >> 3) & 3);
                    a2[w][kcol >> 5][srow][kcol & 7] = (unsigned short)(pk >> 16);
                }
            }
        }
    };

    // GEMM2: a2[w] @ w2f(LDS) -> c2
    auto gemm2 = [&](f32x4 (&c2)[8]) {
        #pragma unroll
        for (int nt = 0; nt < 8; ++nt) c2[nt] = (f32x4){0.f, 0.f, 0.f, 0.f};
        __builtin_amdgcn_s_setprio(1);
        #pragma unroll
        for (int kt2 = 0; kt2 < 4; ++kt2) {
            short8 af;
            __builtin_memcpy(&af, &a2[w][kt2][srl][0], 16);
            #pragma unroll
            for (int nt = 0; nt < 8; ++nt) {
                const short8 bf = ((const short8*)(wlds + W1F_U4))[(kt2 * 8 + nt) * 64 + lane];
                c2[nt] = __builtin_amdgcn_mfma_f32_16x16x32_bf16(af, bf, c2[nt], 0, 0, 0);
            }
        }
        __builtin_amdgcn_s_setprio(0);
    };

    // epilogue 2: +b2, LN2, mask, pool
    auto epi2 = [&](f32x4 (&c2)[8], int rowbase) {
        f32x4 e2[8];
        #pragma unroll
        for (int nt = 0; nt < 8; ++nt) e2[nt] = ecoef2[nt * 16 + c];
        #pragma unroll
        for (int r = 0; r < 4; ++r) {
            float v[8], s = 0.f, q = 0.f;
            #pragma unroll
            for (int nt = 0; nt < 8; ++nt) {
                v[nt] = c2[nt][r] + e2[nt][0];
                s += v[nt]; q = fmaf(v[nt], v[nt], q);
            }
            s = red16(s); q = red16(q);
            const float mean = s * (1.f / 128.f);
            const float var  = fmaxf(q * (1.f / 128.f) - mean * mean, 0.f);
            const float rstd = rsqrtf(var + LN_EPS);
            const float msk = ((rowbase + 4 * g + r) < len) ? 1.f : 0.f;
            #pragma unroll
            for (int nt = 0; nt < 8; ++nt) {
                const float y = fmaf((v[nt] - mean) * rstd, e2[nt][1], e2[nt][2]);
                pool[nt] = fmaf(y, msk, pool[nt]);
            }
        }
    };

    for (int st = (w >> 1); st < nst; st += 4) {
        const int R0 = st << 5;
        int   id[2]; float dn[2];
        #pragma unroll
        for (int mt = 0; mt < 2; ++mt) {
            const int p  = R0 + mt * 16 + c;
            const int pc = min(p, L - 1);
            id[mt]  = tids[b * L + pc];
            dn[mt]  = dates[b * L + pc] * (1.f / 1825.f);
        }
        const bool amt1 = (R0 + 16) < len;             // wave-uniform

        // temporal A-frags (row = c, k-chunk = g*8..g*8+7); coeffs from LDS
        short8 tfrag[2];
        #pragma unroll
        for (int mt = 0; mt < 2; ++mt) {
            const float d  = dn[mt];
            const float tm = fmaf(d, Sw, Sb) * (1.f / 32.f);
            float tv = fmaf(d * d, Sww, fmaf(2.f * d, Swb, Sbb)) * (1.f / 32.f) - tm * tm;
            const float trs = rsqrtf(fmaxf(tv, 0.f) + LN_EPS);
            const int j0 = g * 8;
            uint4v r;
            #pragma unroll
            for (int j2 = 0; j2 < 4; ++j2) {
                const f32x4 t0 = tcoef[j0 + 2*j2];
                const f32x4 t1 = tcoef[j0 + 2*j2 + 1];
                const float y0 = fmaf((fmaf(d, t0[0], t0[1]) - tm) * trs, t0[2], t0[3]);
                const float y1 = fmaf((fmaf(d, t1[0], t1[1]) - tm) * trs, t1[2], t1[3]);
                r[j2] = cvt_pk_bf16(gelu_f(y0), gelu_f(y1));
            }
            union { uint4v u; short8 s; } cv; cv.u = r;
            tfrag[mt] = cv.s;
        }

        // ---------------- GEMM1: [2mt x 16][K=160] @ w1f(LDS) ----------------
        f32x4 acc[2][8];
        #pragma unroll
        for (int mt = 0; mt < 2; ++mt)
            #pragma unroll
            for (int nt = 0; nt < 8; ++nt) acc[mt][nt] = (f32x4){0.f, 0.f, 0.f, 0.f};
        __builtin_amdgcn_s_setprio(1);
        #pragma unroll
        for (int kt = 0; kt < 5; ++kt) {
            short8 af[2];
            if (kt < 4) {
                #pragma unroll
                for (int mt = 0; mt < 2; ++mt)
                    af[mt] = *(const short8*)(emb16 + id[mt] * 128 + kt * 32 + g * 8);
            } else {
                #pragma unroll
                for (int mt = 0; mt < 2; ++mt) af[mt] = tfrag[mt];
            }
            #pragma unroll
            for (int nt = 0; nt < 8; ++nt) {
                const short8 bf = ((const short8*)wlds)[(kt * 8 + nt) * 64 + lane];
                #pragma unroll
                for (int mt = 0; mt < 2; ++mt)
                    acc[mt][nt] = __builtin_amdgcn_mfma_f32_16x16x32_bf16(af[mt], bf, acc[mt][nt], 0, 0, 0);
            }
        }
        __builtin_amdgcn_s_setprio(0);

        // ---- strictly serial per-mt (round-7 overlap spilled; do not re-add) ----
        f32x4 acc2[8];

        epi1(acc[0]);
        asm volatile("" ::: "memory");                 // order a2 W->R (DS in-order)
        gemm2(acc2);
        asm volatile("" ::: "memory");                 // order a2 R -> next W
        epi2(acc2, R0);

        if (amt1) {
            epi1(acc[1]);
            asm volatile("" ::: "memory");
            gemm2(acc2);
            asm volatile("" ::: "memory");
            epi2(acc2, R0 + 16);
        }
    }

    // wave-level pool reduce (over g groups), then cross-wave combine in LDS
    #pragma unroll
    for (int nt = 0; nt < 8; ++nt) {
        float tv = pool[nt];
        tv += __shfl_xor(tv, 16);
        tv += __shfl_xor(tv, 32);
        pool[nt] = tv;
    }
    if (g == 0) {
        #pragma unroll
        for (int nt = 0; nt < 8; ++nt) poolbuf[row][w >> 1][nt * 16 + c] = pool[nt];
    }
    __syncthreads();
    if (tid < 256) {
        const int r2  = tid >> 7;                      // which row of the pair
        const int col = tid & 127;
        const int bo  = blockIdx.x * 2 + r2;
        if (bo < B) {
            const int len2 = min(max(lengths[bo], 0), L);
            const float s = poolbuf[r2][0][col] + poolbuf[r2][1][col]
                          + poolbuf[r2][2][col] + poolbuf[r2][3][col];
            out[bo * 128 + col] = (len2 > 0) ? s / (float)len2 : 0.f;
        }
    }
}

extern "C" void kernel_launch(void* const* d_in, const int* in_sizes, int n_in,
                              void* d_out, int out_size, void* d_ws, size_t ws_size,
                              hipStream_t stream) {
    const int*   tids    = (const int*)  d_in[0];
    const float* dates   = (const float*)d_in[1];
    const int*   lengths = (const int*)  d_in[2];
    const float* emb     = (const float*)d_in[3];
    const float* tp_w    = (const float*)d_in[4];
    const float* tp_b    = (const float*)d_in[5];
    const float* tp_lnw  = (const float*)d_in[6];
    const float* tp_lnb  = (const float*)d_in[7];
    const float* w1      = (const float*)d_in[8];
    const float* b1      = (const float*)d_in[9];
    const float* ln1w    = (const float*)d_in[10];
    const float* ln1b    = (const float*)d_in[11];
    const float* w2      = (const float*)d_in[12];
    const float* b2      = (const float*)d_in[13];
    const float* ln2w    = (const float*)d_in[14];
    const float* ln2b    = (const float*)d_in[15];
    float* out = (float*)d_out;

    const int B = in_sizes[2];
    const int L = in_sizes[0] / B;
    const int emb_pairs = in_sizes[3] / 2;

    hipLaunchKernelGGL(prep_kernel, dim3(32), dim3(256), 0, stream,
                       w1, w2, emb, tp_w, tp_b, (unsigned*)d_ws, emb_pairs);
    hipLaunchKernelGGL(encoder_mfma, dim3((B + 1) / 2), dim3(512), 0, stream,
                       tids, dates, lengths, tp_w, tp_b, tp_lnw, tp_lnb,
                       b1, ln1w, ln1b, b2, ln2w, ln2b,
                       (const unsigned*)d_ws, out, B, L, emb_pairs);
}

// Round 9
// 214.014 us; speedup vs baseline: 1.5522x; 1.1169x over previous
//
#include <hip/hip_runtime.h>
#include <cmath>

#define LN_EPS 1e-5f

typedef float  f32x4  __attribute__((ext_vector_type(4)));
typedef short  short8 __attribute__((ext_vector_type(8)));
typedef unsigned int uint4v __attribute__((ext_vector_type(4)));

// ws layout (bytes):
//   w1f  : 5*8*64*16 = 40960   (uint4 frags, B-operand layout, bf16)
//   w2f  : 4*8*64*16 = 32768
//   emb16: NUM_TYPES*128*2     (row-major bf16)
//   tps  : 5 floats (uniform temporal-LN closed-form sums)
#define W1F_U4 2560   // 5*8*64
#define W2F_U4 2048   // 4*8*64
#define WLDS_U4 4608  // staged in LDS per block

__device__ __forceinline__ unsigned short f32_bf16_rne(float f) {
    union { float f; unsigned u; } v; v.f = f;
    unsigned r = v.u + 0x7FFFu + ((v.u >> 16) & 1u);
    return (unsigned short)(r >> 16);
}

// packed f32->bf16 (RNE), 1 VALU op for 2 elements
__device__ __forceinline__ unsigned cvt_pk_bf16(float lo, float hi) {
    unsigned r;
    asm("v_cvt_pk_bf16_f32 %0, %1, %2" : "=v"(r) : "v"(lo), "v"(hi));
    return r;
}

// exact-erf GELU via Abramowitz&Stegun 7.1.26 (|err| <= 1.5e-7)
__device__ __forceinline__ float gelu_f(float x) {
    float ax = fabsf(x);
    float a  = ax * 0.70710678118654752f;          // |x|/sqrt(2)
    float t  = __builtin_amdgcn_rcpf(fmaf(0.3275911f, a, 1.0f));
    float p  = t * fmaf(t, fmaf(t, fmaf(t, fmaf(t, 1.061405429f, -1.453152027f),
                                        1.421413741f), -0.284496736f), 0.254829592f);
    float e  = __builtin_amdgcn_exp2f(-1.44269504089f * a * a);
    float E  = fmaf(-p, e, 1.0f);                  // erf(|x|/sqrt2)
    return 0.5f * fmaf(ax, E, x);                  // 0.5*(x + |x|*erf)
}

// DPP row-rotate add: sum over the 16-lane DPP row, all lanes get the result.
template<int C>
__device__ __forceinline__ float dpp_radd(float x) {
    int t = __builtin_amdgcn_update_dpp(0, __builtin_bit_cast(int, x), C, 0xF, 0xF, true);
    return x + __builtin_bit_cast(float, t);
}
__device__ __forceinline__ float red16(float x) {
    x = dpp_radd<0x128>(x);   // row_ror:8
    x = dpp_radd<0x124>(x);   // row_ror:4
    x = dpp_radd<0x122>(x);   // row_ror:2
    x = dpp_radd<0x121>(x);   // row_ror:1
    return x;
}

// -------- prep: swizzle w1/w2 into MFMA B-fragment layout (bf16), convert emb
//          to bf16 rows, compute temporal-LN sums. Re-run every call.
__global__ void prep_kernel(const float* __restrict__ w1, const float* __restrict__ w2,
                            const float* __restrict__ emb,
                            const float* __restrict__ tp_w, const float* __restrict__ tp_b,
                            unsigned* __restrict__ ws, int emb_pairs) {
    const int tid = blockIdx.x * 256 + threadIdx.x;   // 8192 threads
    uint4v* w1f = (uint4v*)ws;
    uint4v* w2f = w1f + W1F_U4;
    unsigned* emb16 = (unsigned*)(w2f + W2F_U4);

    for (int i = tid; i < W1F_U4; i += 8192) {        // frag(kt,nt,lane): B[k][n]
        const int lane = i & 63, nt = (i >> 6) & 7, kt = i >> 9;
        const int k0 = kt * 32 + (lane >> 4) * 8, n = nt * 16 + (lane & 15);
        uint4v r;
        #pragma unroll
        for (int j2 = 0; j2 < 4; ++j2) {
            unsigned lo = f32_bf16_rne(w1[(k0 + 2 * j2) * 128 + n]);
            unsigned hi = f32_bf16_rne(w1[(k0 + 2 * j2 + 1) * 128 + n]);
            r[j2] = lo | (hi << 16);
        }
        w1f[i] = r;
    }
    for (int i = tid; i < W2F_U4; i += 8192) {
        const int lane = i & 63, nt = (i >> 6) & 7, kt = i >> 9;
        const int k0 = kt * 32 + (lane >> 4) * 8, n = nt * 16 + (lane & 15);
        uint4v r;
        #pragma unroll
        for (int j2 = 0; j2 < 4; ++j2) {
            unsigned lo = f32_bf16_rne(w2[(k0 + 2 * j2) * 128 + n]);
            unsigned hi = f32_bf16_rne(w2[(k0 + 2 * j2 + 1) * 128 + n]);
            r[j2] = lo | (hi << 16);
        }
        w2f[i] = r;
    }
    for (int i = tid; i < emb_pairs; i += 8192) {
        unsigned lo = f32_bf16_rne(emb[2 * i]);
        unsigned hi = f32_bf16_rne(emb[2 * i + 1]);
        emb16[i] = lo | (hi << 16);
    }
    if (tid == 0) {                                   // uniform temporal-LN sums
        float Sw = 0.f, Sb = 0.f, Sww = 0.f, Swb = 0.f, Sbb = 0.f;
        for (int j = 0; j < 32; ++j) {
            const float ww = tp_w[j], bb = tp_b[j];
            Sw += ww; Sb += bb; Sww += ww * ww; Swb += ww * bb; Sbb += bb * bb;
        }
        float* tps = (float*)(emb16 + emb_pairs);
        tps[0] = Sw; tps[1] = Sb; tps[2] = Sww; tps[3] = Swb; tps[4] = Sbb;
    }
}

// -------- main: 768 threads = 12 waves; THREE batch rows per block
//          (row = w>>2, 4 waves per row looping 16-row tiles t = w&3, +4).
//          w1f+w2f (72 KB) staged in LDS once per block.
//
// OCCUPANCY (round 9): round-8 left VGPR_Count=88 -- cash the headroom in.
// __launch_bounds__(768,3): 170-reg unified budget, 1 block/CU, 12 waves =
// 3 waves/SIMD (37.5% cap vs 25%). To fit 170: mt=1 tiles, so peak acc set is
// acc[8]+acc2[8] = 64 AGPR; 88+64 ~= 152 <= 170. The kernel is VALU-work
// bound (round 8: VALU-work ~68 us-equivalent vs MFMA ~14 us), so issue
// capacity is the lever. SPILL TRIPWIRE: WRITE_SIZE > 50 MB => budget blown,
// revert to round-8 regime (512 threads, (512,2), mt=2).
//
// REGISTER DISCIPLINE (rounds 2-5,7): phases strictly serial per tile; no
// cross-phase acc overlap. Coefficients live in LDS. Empty-asm fences only
// (per-wave DS pipe is in-order; no lgkmcnt drain, no sched pin).
__global__ __launch_bounds__(768, 3) void encoder_mfma(
    const int*   __restrict__ tids,  const float* __restrict__ dates,
    const int*   __restrict__ lengths,
    const float* __restrict__ tp_w,  const float* __restrict__ tp_b,
    const float* __restrict__ tp_lnw,const float* __restrict__ tp_lnb,
    const float* __restrict__ b1,    const float* __restrict__ ln1w, const float* __restrict__ ln1b,
    const float* __restrict__ b2,    const float* __restrict__ ln2w, const float* __restrict__ ln2b,
    const unsigned* __restrict__ ws, float* __restrict__ out,
    int B, int L, int emb_pairs)
{
    __shared__ __align__(16) uint4v wlds[WLDS_U4];                // 72 KB: w1f|w2f
    // per-wave C->A transpose scratch (single m-tile): [wave][kt2][row64][j]
    __shared__ __align__(16) unsigned short a2[12][4][64][8];     // 48 KB
    __shared__ float poolbuf[3][4][128];                          // 6 KB
    __shared__ __align__(16) f32x4 tcoef[32];    // {tp_w, tp_b, tp_lnw, tp_lnb}
    __shared__ __align__(16) f32x4 ecoef1[128];  // {b1, ln1w, ln1b, -}
    __shared__ __align__(16) f32x4 ecoef2[128];  // {b2, ln2w, ln2b, -}

    const int tid = threadIdx.x;
    const int lane = tid & 63, w = tid >> 6;          // w in 0..11
    const int c = lane & 15, g = lane >> 4;
    const int row = w >> 2, wr = w & 3;
    const int b   = blockIdx.x * 3 + row;

    // ---- stage weights into LDS (4608 uint4 by 768 threads: 6 each) ----
    #pragma unroll
    for (int i = 0; i < 6; ++i)
        wlds[i * 768 + tid] = ((const uint4v*)ws)[i * 768 + tid];

    const unsigned short* emb16 = (const unsigned short*)((const uint4v*)ws + W1F_U4 + W2F_U4);
    const float* tps = (const float*)(emb16 + emb_pairs * 2);

    if (tid < 32)  tcoef[tid]  = (f32x4){tp_w[tid], tp_b[tid], tp_lnw[tid], tp_lnb[tid]};
    if (tid < 128) {
        ecoef1[tid] = (f32x4){b1[tid], ln1w[tid], ln1b[tid], 0.f};
        ecoef2[tid] = (f32x4){b2[tid], ln2w[tid], ln2b[tid], 0.f};
    }
    __syncthreads();

    const float Sw = tps[0], Sb = tps[1], Sww = tps[2], Swb = tps[3], Sbb = tps[4];

    const int len = (b < B) ? min(max(lengths[b], 0), L) : 0;
    const int ntiles = (len + 15) >> 4;               // 16-row tiles, 0..13

    float pool[8];
    #pragma unroll
    for (int nt = 0; nt < 8; ++nt) pool[nt] = 0.f;
    const int srl = lane ^ ((lane >> 3) & 3);          // swizzled GEMM2 read row

    for (int t = wr; t < ntiles; t += 4) {
        const int R0 = t << 4;
        const int pc = min(R0 + c, L - 1);
        const int id = tids[b * L + pc];
        const float d = dates[b * L + pc] * (1.f / 1825.f);

        // temporal A-frag (row = c, k-chunk = g*8..g*8+7); coeffs from LDS
        short8 tfrag;
        {
            const float tm = fmaf(d, Sw, Sb) * (1.f / 32.f);
            float tv = fmaf(d * d, Sww, fmaf(2.f * d, Swb, Sbb)) * (1.f / 32.f) - tm * tm;
            const float trs = rsqrtf(fmaxf(tv, 0.f) + LN_EPS);
            const int j0 = g * 8;
            uint4v r;
            #pragma unroll
            for (int j2 = 0; j2 < 4; ++j2) {
                const f32x4 t0 = tcoef[j0 + 2*j2];
                const f32x4 t1 = tcoef[j0 + 2*j2 + 1];
                const float y0 = fmaf((fmaf(d, t0[0], t0[1]) - tm) * trs, t0[2], t0[3]);
                const float y1 = fmaf((fmaf(d, t1[0], t1[1]) - tm) * trs, t1[2], t1[3]);
                r[j2] = cvt_pk_bf16(gelu_f(y0), gelu_f(y1));
            }
            union { uint4v u; short8 s; } cv; cv.u = r;
            tfrag = cv.s;
        }

        // ---------------- GEMM1: [16 x K=160] @ w1f(LDS) ----------------
        f32x4 acc[8];
        #pragma unroll
        for (int nt = 0; nt < 8; ++nt) acc[nt] = (f32x4){0.f, 0.f, 0.f, 0.f};
        __builtin_amdgcn_s_setprio(1);
        #pragma unroll
        for (int kt = 0; kt < 5; ++kt) {
            const short8 af = (kt < 4) ? *(const short8*)(emb16 + id * 128 + kt * 32 + g * 8)
                                       : tfrag;
            #pragma unroll
            for (int nt = 0; nt < 8; ++nt) {
                const short8 bf = ((const short8*)wlds)[(kt * 8 + nt) * 64 + lane];
                acc[nt] = __builtin_amdgcn_mfma_f32_16x16x32_bf16(af, bf, acc[nt], 0, 0, 0);
            }
        }
        __builtin_amdgcn_s_setprio(0);

        // ------- epilogue 1: +b1, LN1 (DPP), GELU -> bf16 a2[w] (swizzled) -------
        {
            f32x4 e1[8];
            #pragma unroll
            for (int nt = 0; nt < 8; ++nt) e1[nt] = ecoef1[nt * 16 + c];
            #pragma unroll
            for (int r = 0; r < 4; ++r) {
                float v[8], s = 0.f, q = 0.f;
                #pragma unroll
                for (int nt = 0; nt < 8; ++nt) {
                    v[nt] = acc[nt][r] + e1[nt][0];
                    s += v[nt]; q = fmaf(v[nt], v[nt], q);
                }
                s = red16(s); q = red16(q);
                const float mean = s * (1.f / 128.f);
                const float var  = fmaxf(q * (1.f / 128.f) - mean * mean, 0.f);
                const float rstd = rsqrtf(var + LN_EPS);
                const int mrow = 4 * g + r;
                #pragma unroll
                for (int n2 = 0; n2 < 4; ++n2) {
                    const float y0 = gelu_f(fmaf((v[2*n2]   - mean) * rstd, e1[2*n2][1],   e1[2*n2][2]));
                    const float y1 = gelu_f(fmaf((v[2*n2+1] - mean) * rstd, e1[2*n2+1][1], e1[2*n2+1][2]));
                    const unsigned pk = cvt_pk_bf16(y0, y1);
                    {
                        const int kcol  = (2*n2) * 16 + c;
                        const int row64 = ((kcol >> 3) & 3) * 16 + mrow;
                        const int srow  = row64 ^ ((row64 >> 3) & 3);
                        a2[w][kcol >> 5][srow][kcol & 7] = (unsigned short)(pk & 0xffffu);
                    }
                    {
                        const int kcol  = (2*n2+1) * 16 + c;
                        const int row64 = ((kcol >> 3) & 3) * 16 + mrow;
                        const int srow  = row64 ^ ((row64 >> 3) & 3);
                        a2[w][kcol >> 5][srow][kcol & 7] = (unsigned short)(pk >> 16);
                    }
                }
            }
        }

        asm volatile("" ::: "memory");                 // order a2 W->R (DS in-order)

        // ---------------- GEMM2: a2[w] @ w2f(LDS) ----------------
        f32x4 acc2[8];
        #pragma unroll
        for (int nt = 0; nt < 8; ++nt) acc2[nt] = (f32x4){0.f, 0.f, 0.f, 0.f};
        __builtin_amdgcn_s_setprio(1);
        #pragma unroll
        for (int kt2 = 0; kt2 < 4; ++kt2) {
            short8 af;
            __builtin_memcpy(&af, &a2[w][kt2][srl][0], 16);
            #pragma unroll
            for (int nt = 0; nt < 8; ++nt) {
                const short8 bf = ((const short8*)(wlds + W1F_U4))[(kt2 * 8 + nt) * 64 + lane];
                acc2[nt] = __builtin_amdgcn_mfma_f32_16x16x32_bf16(af, bf, acc2[nt], 0, 0, 0);
            }
        }
        __builtin_amdgcn_s_setprio(0);

        asm volatile("" ::: "memory");                 // order a2 R -> next tile W

        // ---------------- epilogue 2: +b2, LN2, mask, pool ----------------
        {
            f32x4 e2[8];
            #pragma unroll
            for (int nt = 0; nt < 8; ++nt) e2[nt] = ecoef2[nt * 16 + c];
            #pragma unroll
            for (int r = 0; r < 4; ++r) {
                float v[8], s = 0.f, q = 0.f;
                #pragma unroll
                for (int nt = 0; nt < 8; ++nt) {
                    v[nt] = acc2[nt][r] + e2[nt][0];
                    s += v[nt]; q = fmaf(v[nt], v[nt], q);
                }
                s = red16(s); q = red16(q);
                const float mean = s * (1.f / 128.f);
                const float var  = fmaxf(q * (1.f / 128.f) - mean * mean, 0.f);
                const float rstd = rsqrtf(var + LN_EPS);
                const float msk = ((R0 + 4 * g + r) < len) ? 1.f : 0.f;
                #pragma unroll
                for (int nt = 0; nt < 8; ++nt) {
                    const float y = fmaf((v[nt] - mean) * rstd, e2[nt][1], e2[nt][2]);
                    pool[nt] = fmaf(y, msk, pool[nt]);
                }
            }
        }
    }

    // wave-level pool reduce (over g groups), then cross-wave combine in LDS
    #pragma unroll
    for (int nt = 0; nt < 8; ++nt) {
        float tv = pool[nt];
        tv += __shfl_xor(tv, 16);
        tv += __shfl_xor(tv, 32);
        pool[nt] = tv;
    }
    if (g == 0) {
        #pragma unroll
        for (int nt = 0; nt < 8; ++nt) poolbuf[row][wr][nt * 16 + c] = pool[nt];
    }
    __syncthreads();
    if (tid < 384) {
        const int r3  = tid >> 7;                      // which row of the triple
        const int col = tid & 127;
        const int bo  = blockIdx.x * 3 + r3;
        if (bo < B) {
            const int len2 = min(max(lengths[bo], 0), L);
            const float s = poolbuf[r3][0][col] + poolbuf[r3][1][col]
                          + poolbuf[r3][2][col] + poolbuf[r3][3][col];
            out[bo * 128 + col] = (len2 > 0) ? s / (float)len2 : 0.f;
        }
    }
}

extern "C" void kernel_launch(void* const* d_in, const int* in_sizes, int n_in,
                              void* d_out, int out_size, void* d_ws, size_t ws_size,
                              hipStream_t stream) {
    const int*   tids    = (const int*)  d_in[0];
    const float* dates   = (const float*)d_in[1];
    const int*   lengths = (const int*)  d_in[2];
    const float* emb     = (const float*)d_in[3];
    const float* tp_w    = (const float*)d_in[4];
    const float* tp_b    = (const float*)d_in[5];
    const float* tp_lnw  = (const float*)d_in[6];
    const float* tp_lnb  = (const float*)d_in[7];
    const float* w1      = (const float*)d_in[8];
    const float* b1      = (const float*)d_in[9];
    const float* ln1w    = (const float*)d_in[10];
    const float* ln1b    = (const float*)d_in[11];
    const float* w2      = (const float*)d_in[12];
    const float* b2      = (const float*)d_in[13];
    const float* ln2w    = (const float*)d_in[14];
    const float* ln2b    = (const float*)d_in[15];
    float* out = (float*)d_out;

    const int B = in_sizes[2];
    const int L = in_sizes[0] / B;
    const int emb_pairs = in_sizes[3] / 2;

    hipLaunchKernelGGL(prep_kernel, dim3(32), dim3(256), 0, stream,
                       w1, w2, emb, tp_w, tp_b, (unsigned*)d_ws, emb_pairs);
    hipLaunchKernelGGL(encoder_mfma, dim3((B + 2) / 3), dim3(768), 0, stream,
                       tids, dates, lengths, tp_w, tp_b, tp_lnw, tp_lnb,
                       b1, ln1w, ln1b, b2, ln2w, ln2b,
                       (const unsigned*)d_ws, out, B, L, emb_pairs);
}

// Round 10
// 211.486 us; speedup vs baseline: 1.5708x; 1.0120x over previous
//
#include <hip/hip_runtime.h>
#include <cmath>

#define LN_EPS 1e-5f

typedef float  f32x4  __attribute__((ext_vector_type(4)));
typedef short  short8 __attribute__((ext_vector_type(8)));
typedef unsigned int uint4v __attribute__((ext_vector_type(4)));

// ws layout (uint4 units):
//   w1tf : 512   (temporal K-slice of w1, k=128..159, B-frag layout, bf16)
//   w2f  : 2048  (B-frag layout, bf16)
//   E1   : 1650  (50 x 132 f32: emb @ w1[:128] table, 128 cols + 4 pad)
//   tps  : 5 floats (uniform temporal-LN closed-form sums)
// E1 INSIGHT (round 10): only NUM_TYPES=50 distinct embedding rows exist, so
// emb@w1[:128] (45% of all MFMA FLOPs) is a 50x128 table computed once in
// prep (exact f32 -- MORE accurate than the bf16 MFMA it replaces). Per tile
// the embedding contribution becomes an LDS gather; GEMM1 shrinks to the
// K=32 temporal slice. Row stride 132 so gather bank-windows spread by id.
#define W1TF_U4 512
#define W2F_U4  2048
#define E1_U4   1650
#define WLDS_U4 2560   // w1tf + w2f staged to LDS

__device__ __forceinline__ unsigned short f32_bf16_rne(float f) {
    union { float f; unsigned u; } v; v.f = f;
    unsigned r = v.u + 0x7FFFu + ((v.u >> 16) & 1u);
    return (unsigned short)(r >> 16);
}

// packed f32->bf16 (RNE), 1 VALU op for 2 elements
__device__ __forceinline__ unsigned cvt_pk_bf16(float lo, float hi) {
    unsigned r;
    asm("v_cvt_pk_bf16_f32 %0, %1, %2" : "=v"(r) : "v"(lo), "v"(hi));
    return r;
}

// exact-erf GELU via Abramowitz&Stegun 7.1.26 (|err| <= 1.5e-7)
__device__ __forceinline__ float gelu_f(float x) {
    float ax = fabsf(x);
    float a  = ax * 0.70710678118654752f;          // |x|/sqrt(2)
    float t  = __builtin_amdgcn_rcpf(fmaf(0.3275911f, a, 1.0f));
    float p  = t * fmaf(t, fmaf(t, fmaf(t, fmaf(t, 1.061405429f, -1.453152027f),
                                        1.421413741f), -0.284496736f), 0.254829592f);
    float e  = __builtin_amdgcn_exp2f(-1.44269504089f * a * a);
    float E  = fmaf(-p, e, 1.0f);                  // erf(|x|/sqrt2)
    return 0.5f * fmaf(ax, E, x);                  // 0.5*(x + |x|*erf)
}

// DPP row-rotate add: sum over the 16-lane DPP row, all lanes get the result.
template<int C>
__device__ __forceinline__ float dpp_radd(float x) {
    int t = __builtin_amdgcn_update_dpp(0, __builtin_bit_cast(int, x), C, 0xF, 0xF, true);
    return x + __builtin_bit_cast(float, t);
}
__device__ __forceinline__ float red16(float x) {
    x = dpp_radd<0x128>(x);   // row_ror:8
    x = dpp_radd<0x124>(x);   // row_ror:4
    x = dpp_radd<0x122>(x);   // row_ror:2
    x = dpp_radd<0x121>(x);   // row_ror:1
    return x;
}

// -------- prep: build w1tf/w2f B-frags (bf16), E1 table (f32), temporal-LN
//          sums. Re-run every call.
__global__ void prep_kernel(const float* __restrict__ w1, const float* __restrict__ w2,
                            const float* __restrict__ emb,
                            const float* __restrict__ tp_w, const float* __restrict__ tp_b,
                            unsigned* __restrict__ ws) {
    const int tid = blockIdx.x * 256 + threadIdx.x;   // 8192 threads
    uint4v* w1tf = (uint4v*)ws;
    uint4v* w2f  = w1tf + W1TF_U4;
    float*  E1   = (float*)(w2f + W2F_U4);
    float*  tps  = E1 + 6600;

    for (int i = tid; i < W1TF_U4; i += 8192) {       // temporal slice frags
        const int lane = i & 63, nt = i >> 6;         // nt 0..7
        const int k0 = 128 + (lane >> 4) * 8, n = nt * 16 + (lane & 15);
        uint4v r;
        #pragma unroll
        for (int j2 = 0; j2 < 4; ++j2) {
            unsigned lo = f32_bf16_rne(w1[(k0 + 2 * j2) * 128 + n]);
            unsigned hi = f32_bf16_rne(w1[(k0 + 2 * j2 + 1) * 128 + n]);
            r[j2] = lo | (hi << 16);
        }
        w1tf[i] = r;
    }
    for (int i = tid; i < W2F_U4; i += 8192) {
        const int lane = i & 63, nt = (i >> 6) & 7, kt = i >> 9;
        const int k0 = kt * 32 + (lane >> 4) * 8, n = nt * 16 + (lane & 15);
        uint4v r;
        #pragma unroll
        for (int j2 = 0; j2 < 4; ++j2) {
            unsigned lo = f32_bf16_rne(w2[(k0 + 2 * j2) * 128 + n]);
            unsigned hi = f32_bf16_rne(w2[(k0 + 2 * j2 + 1) * 128 + n]);
            r[j2] = lo | (hi << 16);
        }
        w2f[i] = r;
    }
    // E1[t][n] = sum_k emb[t][k] * w1[k][n]  (f32 exact; coalesced over n)
    if (tid < 6400) {
        const int t = tid >> 7, n = tid & 127;
        float s = 0.f;
        for (int k = 0; k < 128; ++k)
            s = fmaf(emb[t * 128 + k], w1[k * 128 + n], s);
        E1[t * 132 + n] = s;
    }
    if (tid == 0) {                                   // uniform temporal-LN sums
        float Sw = 0.f, Sb = 0.f, Sww = 0.f, Swb = 0.f, Sbb = 0.f;
        for (int j = 0; j < 32; ++j) {
            const float ww = tp_w[j], bb = tp_b[j];
            Sw += ww; Sb += bb; Sww += ww * ww; Swb += ww * bb; Sbb += bb * bb;
        }
        tps[0] = Sw; tps[1] = Sb; tps[2] = Sww; tps[3] = Swb; tps[4] = Sbb;
    }
}

// -------- main: 768 threads = 12 waves; THREE batch rows per block
//          (row = w>>2, 4 waves per row looping 16-row tiles t = w&3, +4).
//          w1tf+w2f (40 KB) + E1 (26.4 KB) staged in LDS once per block.
//
// GEMM1 is now: acc init = E1 gather (per MFMA C-layout row 4g+r, col nt*16+c)
// + 8 MFMAs for the temporal K=32 slice. No per-tile global emb loads at all.
//
// REGISTER DISCIPLINE (rounds 2-5,7): (768,3) = 170-reg budget, measured 68
// arch + 64 acc with headroom. Phases strictly serial per tile; coefficients
// in LDS; empty-asm fences only (per-wave DS pipe is in-order).
// SPILL TRIPWIRE: WRITE_SIZE > 50 MB => revert.
__global__ __launch_bounds__(768, 3) void encoder_mfma(
    const int*   __restrict__ tids,  const float* __restrict__ dates,
    const int*   __restrict__ lengths,
    const float* __restrict__ tp_w,  const float* __restrict__ tp_b,
    const float* __restrict__ tp_lnw,const float* __restrict__ tp_lnb,
    const float* __restrict__ b1,    const float* __restrict__ ln1w, const float* __restrict__ ln1b,
    const float* __restrict__ b2,    const float* __restrict__ ln2w, const float* __restrict__ ln2b,
    const unsigned* __restrict__ ws, float* __restrict__ out,
    int B, int L)
{
    __shared__ __align__(16) uint4v wlds[WLDS_U4];                // 40 KB: w1tf|w2f
    __shared__ __align__(16) float  E1lds[6600];                  // 26.4 KB
    // per-wave C->A transpose scratch (single m-tile): [wave][kt2][row64][j]
    __shared__ __align__(16) unsigned short a2[12][4][64][8];     // 48 KB
    __shared__ float poolbuf[3][4][128];                          // 6 KB
    __shared__ __align__(16) f32x4 tcoef[32];    // {tp_w, tp_b, tp_lnw, tp_lnb}
    __shared__ __align__(16) f32x4 ecoef1[128];  // {b1, ln1w, ln1b, -}
    __shared__ __align__(16) f32x4 ecoef2[128];  // {b2, ln2w, ln2b, -}

    const int tid = threadIdx.x;
    const int lane = tid & 63, w = tid >> 6;          // w in 0..11
    const int c = lane & 15, g = lane >> 4;
    const int row = w >> 2, wr = w & 3;
    const int b   = blockIdx.x * 3 + row;

    // ---- stage weights + E1 into LDS ----
    for (int i = tid; i < WLDS_U4; i += 768)
        wlds[i] = ((const uint4v*)ws)[i];
    for (int i = tid; i < E1_U4; i += 768)
        ((uint4v*)E1lds)[i] = ((const uint4v*)ws)[WLDS_U4 + i];

    const float* tps = (const float*)((const uint4v*)ws + WLDS_U4 + E1_U4);

    if (tid < 32)  tcoef[tid]  = (f32x4){tp_w[tid], tp_b[tid], tp_lnw[tid], tp_lnb[tid]};
    if (tid < 128) {
        ecoef1[tid] = (f32x4){b1[tid], ln1w[tid], ln1b[tid], 0.f};
        ecoef2[tid] = (f32x4){b2[tid], ln2w[tid], ln2b[tid], 0.f};
    }
    __syncthreads();

    const float Sw = tps[0], Sb = tps[1], Sww = tps[2], Swb = tps[3], Sbb = tps[4];

    const int len = (b < B) ? min(max(lengths[b], 0), L) : 0;
    const int ntiles = (len + 15) >> 4;               // 16-row tiles, 0..13

    float pool[8];
    #pragma unroll
    for (int nt = 0; nt < 8; ++nt) pool[nt] = 0.f;
    const int srl = lane ^ ((lane >> 3) & 3);          // swizzled GEMM2 read row

    for (int t = wr; t < ntiles; t += 4) {
        const int R0 = t << 4;
        const int pc = min(R0 + c, L - 1);
        const float d = dates[b * L + pc] * (1.f / 1825.f);
        // ids for this lane's C-layout rows (4g+r); group-uniform broadcast loads
        int idr[4];
        #pragma unroll
        for (int r = 0; r < 4; ++r)
            idr[r] = tids[b * L + min(R0 + 4 * g + r, L - 1)];

        // temporal A-frag (row = c, k-chunk = g*8..g*8+7); coeffs from LDS
        short8 tfrag;
        {
            const float tm = fmaf(d, Sw, Sb) * (1.f / 32.f);
            float tv = fmaf(d * d, Sww, fmaf(2.f * d, Swb, Sbb)) * (1.f / 32.f) - tm * tm;
            const float trs = rsqrtf(fmaxf(tv, 0.f) + LN_EPS);
            const int j0 = g * 8;
            uint4v r;
            #pragma unroll
            for (int j2 = 0; j2 < 4; ++j2) {
                const f32x4 t0 = tcoef[j0 + 2*j2];
                const f32x4 t1 = tcoef[j0 + 2*j2 + 1];
                const float y0 = fmaf((fmaf(d, t0[0], t0[1]) - tm) * trs, t0[2], t0[3]);
                const float y1 = fmaf((fmaf(d, t1[0], t1[1]) - tm) * trs, t1[2], t1[3]);
                r[j2] = cvt_pk_bf16(gelu_f(y0), gelu_f(y1));
            }
            union { uint4v u; short8 s; } cv; cv.u = r;
            tfrag = cv.s;
        }

        // ---- GEMM1: acc = E1 gather (emb@w1 table) + temporal K=32 MFMA ----
        f32x4 acc[8];
        #pragma unroll
        for (int r = 0; r < 4; ++r) {
            const int e1base = idr[r] * 132 + c;
            #pragma unroll
            for (int nt = 0; nt < 8; ++nt)
                acc[nt][r] = E1lds[e1base + nt * 16];
        }
        __builtin_amdgcn_s_setprio(1);
        #pragma unroll
        for (int nt = 0; nt < 8; ++nt) {
            const short8 bf = ((const short8*)wlds)[nt * 64 + lane];
            acc[nt] = __builtin_amdgcn_mfma_f32_16x16x32_bf16(tfrag, bf, acc[nt], 0, 0, 0);
        }
        __builtin_amdgcn_s_setprio(0);

        // ------- epilogue 1: +b1, LN1 (DPP), GELU -> bf16 a2[w] (swizzled) -------
        {
            f32x4 e1[8];
            #pragma unroll
            for (int nt = 0; nt < 8; ++nt) e1[nt] = ecoef1[nt * 16 + c];
            #pragma unroll
            for (int r = 0; r < 4; ++r) {
                float v[8], s = 0.f, q = 0.f;
                #pragma unroll
                for (int nt = 0; nt < 8; ++nt) {
                    v[nt] = acc[nt][r] + e1[nt][0];
                    s += v[nt]; q = fmaf(v[nt], v[nt], q);
                }
                s = red16(s); q = red16(q);
                const float mean = s * (1.f / 128.f);
                const float var  = fmaxf(q * (1.f / 128.f) - mean * mean, 0.f);
                const float rstd = rsqrtf(var + LN_EPS);
                const int mrow = 4 * g + r;
                #pragma unroll
                for (int n2 = 0; n2 < 4; ++n2) {
                    const float y0 = gelu_f(fmaf((v[2*n2]   - mean) * rstd, e1[2*n2][1],   e1[2*n2][2]));
                    const float y1 = gelu_f(fmaf((v[2*n2+1] - mean) * rstd, e1[2*n2+1][1], e1[2*n2+1][2]));
                    const unsigned pk = cvt_pk_bf16(y0, y1);
                    {
                        const int kcol  = (2*n2) * 16 + c;
                        const int row64 = ((kcol >> 3) & 3) * 16 + mrow;
                        const int srow  = row64 ^ ((row64 >> 3) & 3);
                        a2[w][kcol >> 5][srow][kcol & 7] = (unsigned short)(pk & 0xffffu);
                    }
                    {
                        const int kcol  = (2*n2+1) * 16 + c;
                        const int row64 = ((kcol >> 3) & 3) * 16 + mrow;
                        const int srow  = row64 ^ ((row64 >> 3) & 3);
                        a2[w][kcol >> 5][srow][kcol & 7] = (unsigned short)(pk >> 16);
                    }
                }
            }
        }

        asm volatile("" ::: "memory");                 // order a2 W->R (DS in-order)

        // ---------------- GEMM2: a2[w] @ w2f(LDS) ----------------
        f32x4 acc2[8];
        #pragma unroll
        for (int nt = 0; nt < 8; ++nt) acc2[nt] = (f32x4){0.f, 0.f, 0.f, 0.f};
        __builtin_amdgcn_s_setprio(1);
        #pragma unroll
        for (int kt2 = 0; kt2 < 4; ++kt2) {
            short8 af;
            __builtin_memcpy(&af, &a2[w][kt2][srl][0], 16);
            #pragma unroll
            for (int nt = 0; nt < 8; ++nt) {
                const short8 bf = ((const short8*)(wlds + W1TF_U4))[(kt2 * 8 + nt) * 64 + lane];
                acc2[nt] = __builtin_amdgcn_mfma_f32_16x16x32_bf16(af, bf, acc2[nt], 0, 0, 0);
            }
        }
        __builtin_amdgcn_s_setprio(0);

        asm volatile("" ::: "memory");                 // order a2 R -> next tile W

        // ---------------- epilogue 2: +b2, LN2, mask, pool ----------------
        {
            f32x4 e2[8];
            #pragma unroll
            for (int nt = 0; nt < 8; ++nt) e2[nt] = ecoef2[nt * 16 + c];
            #pragma unroll
            for (int r = 0; r < 4; ++r) {
                float v[8], s = 0.f, q = 0.f;
                #pragma unroll
                for (int nt = 0; nt < 8; ++nt) {
                    v[nt] = acc2[nt][r] + e2[nt][0];
                    s += v[nt]; q = fmaf(v[nt], v[nt], q);
                }
                s = red16(s); q = red16(q);
                const float mean = s * (1.f / 128.f);
                const float var  = fmaxf(q * (1.f / 128.f) - mean * mean, 0.f);
                const float rstd = rsqrtf(var + LN_EPS);
                const float msk = ((R0 + 4 * g + r) < len) ? 1.f : 0.f;
                #pragma unroll
                for (int nt = 0; nt < 8; ++nt) {
                    const float y = fmaf((v[nt] - mean) * rstd, e2[nt][1], e2[nt][2]);
                    pool[nt] = fmaf(y, msk, pool[nt]);
                }
            }
        }
    }

    // wave-level pool reduce (over g groups), then cross-wave combine in LDS
    #pragma unroll
    for (int nt = 0; nt < 8; ++nt) {
        float tv = pool[nt];
        tv += __shfl_xor(tv, 16);
        tv += __shfl_xor(tv, 32);
        pool[nt] = tv;
    }
    if (g == 0) {
        #pragma unroll
        for (int nt = 0; nt < 8; ++nt) poolbuf[row][wr][nt * 16 + c] = pool[nt];
    }
    __syncthreads();
    if (tid < 384) {
        const int r3  = tid >> 7;                      // which row of the triple
        const int col = tid & 127;
        const int bo  = blockIdx.x * 3 + r3;
        if (bo < B) {
            const int len2 = min(max(lengths[bo], 0), L);
            const float s = poolbuf[r3][0][col] + poolbuf[r3][1][col]
                          + poolbuf[r3][2][col] + poolbuf[r3][3][col];
            out[bo * 128 + col] = (len2 > 0) ? s / (float)len2 : 0.f;
        }
    }
}

extern "C" void kernel_launch(void* const* d_in, const int* in_sizes, int n_in,
                              void* d_out, int out_size, void* d_ws, size_t ws_size,
                              hipStream_t stream) {
    const int*   tids    = (const int*)  d_in[0];
    const float* dates   = (const float*)d_in[1];
    const int*   lengths = (const int*)  d_in[2];
    const float* emb     = (const float*)d_in[3];
    const float* tp_w    = (const float*)d_in[4];
    const float* tp_b    = (const float*)d_in[5];
    const float* tp_lnw  = (const float*)d_in[6];
    const float* tp_lnb  = (const float*)d_in[7];
    const float* w1      = (const float*)d_in[8];
    const float* b1      = (const float*)d_in[9];
    const float* ln1w    = (const float*)d_in[10];
    const float* ln1b    = (const float*)d_in[11];
    const float* w2      = (const float*)d_in[12];
    const float* b2      = (const float*)d_in[13];
    const float* ln2w    = (const float*)d_in[14];
    const float* ln2b    = (const float*)d_in[15];
    float* out = (float*)d_out;

    const int B = in_sizes[2];
    const int L = in_sizes[0] / B;

    hipLaunchKernelGGL(prep_kernel, dim3(32), dim3(256), 0, stream,
                       w1, w2, emb, tp_w, tp_b, (unsigned*)d_ws);
    hipLaunchKernelGGL(encoder_mfma, dim3((B + 2) / 3), dim3(768), 0, stream,
                       tids, dates, lengths, tp_w, tp_b, tp_lnw, tp_lnb,
                       b1, ln1w, ln1b, b2, ln2w, ln2b,
                       (const unsigned*)d_ws, out, B, L);
}

// Round 11
// 208.338 us; speedup vs baseline: 1.5945x; 1.0151x over previous
//
#include <hip/hip_runtime.h>
#include <cmath>

#define LN_EPS 1e-5f

typedef float  f32x4  __attribute__((ext_vector_type(4)));
typedef short  short8 __attribute__((ext_vector_type(8)));
typedef unsigned int uint4v __attribute__((ext_vector_type(4)));

// ws layout (uint4 units):
//   w1tf : 512   (temporal K-slice of w1, k=128..159, B-frag layout, bf16)
//   w2f  : 2048  (B-frag layout, bf16)
//   E1   : 1650  (50 x 132 f32: emb @ w1[:128] table, 128 cols + 4 pad)
//   tps  : 5 floats (uniform temporal-LN closed-form sums)
// E1 INSIGHT (round 10): only NUM_TYPES=50 distinct embedding rows exist, so
// emb@w1[:128] (45% of all MFMA FLOPs) is a 50x128 table computed once in
// prep (exact f32). Per tile the embedding contribution is an LDS gather;
// GEMM1 is just the K=32 temporal slice (8 MFMAs).
#define W1TF_U4 512
#define W2F_U4  2048
#define E1_U4   1650
#define WLDS_U4 2560   // w1tf + w2f staged to LDS

__device__ __forceinline__ unsigned short f32_bf16_rne(float f) {
    union { float f; unsigned u; } v; v.f = f;
    unsigned r = v.u + 0x7FFFu + ((v.u >> 16) & 1u);
    return (unsigned short)(r >> 16);
}

// packed f32->bf16 (RNE), 1 VALU op for 2 elements
__device__ __forceinline__ unsigned cvt_pk_bf16(float lo, float hi) {
    unsigned r;
    asm("v_cvt_pk_bf16_f32 %0, %1, %2" : "=v"(r) : "v"(lo), "v"(hi));
    return r;
}

// exact-erf GELU via Abramowitz&Stegun 7.1.26 (|err| <= 1.5e-7)
__device__ __forceinline__ float gelu_f(float x) {
    float ax = fabsf(x);
    float a  = ax * 0.70710678118654752f;          // |x|/sqrt(2)
    float t  = __builtin_amdgcn_rcpf(fmaf(0.3275911f, a, 1.0f));
    float p  = t * fmaf(t, fmaf(t, fmaf(t, fmaf(t, 1.061405429f, -1.453152027f),
                                        1.421413741f), -0.284496736f), 0.254829592f);
    float e  = __builtin_amdgcn_exp2f(-1.44269504089f * a * a);
    float E  = fmaf(-p, e, 1.0f);                  // erf(|x|/sqrt2)
    return 0.5f * fmaf(ax, E, x);                  // 0.5*(x + |x|*erf)
}

// DPP row-rotate add: sum over the 16-lane DPP row, all lanes get the result.
template<int C>
__device__ __forceinline__ float dpp_radd(float x) {
    int t = __builtin_amdgcn_update_dpp(0, __builtin_bit_cast(int, x), C, 0xF, 0xF, true);
    return x + __builtin_bit_cast(float, t);
}
__device__ __forceinline__ float red16(float x) {
    x = dpp_radd<0x128>(x);   // row_ror:8
    x = dpp_radd<0x124>(x);   // row_ror:4
    x = dpp_radd<0x122>(x);   // row_ror:2
    x = dpp_radd<0x121>(x);   // row_ror:1
    return x;
}

// -------- prep: build w1tf/w2f B-frags (bf16), E1 table (f32), temporal-LN
//          sums. Re-run every call.
__global__ void prep_kernel(const float* __restrict__ w1, const float* __restrict__ w2,
                            const float* __restrict__ emb,
                            const float* __restrict__ tp_w, const float* __restrict__ tp_b,
                            unsigned* __restrict__ ws) {
    const int tid = blockIdx.x * 256 + threadIdx.x;   // 8192 threads
    uint4v* w1tf = (uint4v*)ws;
    uint4v* w2f  = w1tf + W1TF_U4;
    float*  E1   = (float*)(w2f + W2F_U4);
    float*  tps  = E1 + 6600;

    for (int i = tid; i < W1TF_U4; i += 8192) {       // temporal slice frags
        const int lane = i & 63, nt = i >> 6;         // nt 0..7
        const int k0 = 128 + (lane >> 4) * 8, n = nt * 16 + (lane & 15);
        uint4v r;
        #pragma unroll
        for (int j2 = 0; j2 < 4; ++j2) {
            unsigned lo = f32_bf16_rne(w1[(k0 + 2 * j2) * 128 + n]);
            unsigned hi = f32_bf16_rne(w1[(k0 + 2 * j2 + 1) * 128 + n]);
            r[j2] = lo | (hi << 16);
        }
        w1tf[i] = r;
    }
    for (int i = tid; i < W2F_U4; i += 8192) {
        const int lane = i & 63, nt = (i >> 6) & 7, kt = i >> 9;
        const int k0 = kt * 32 + (lane >> 4) * 8, n = nt * 16 + (lane & 15);
        uint4v r;
        #pragma unroll
        for (int j2 = 0; j2 < 4; ++j2) {
            unsigned lo = f32_bf16_rne(w2[(k0 + 2 * j2) * 128 + n]);
            unsigned hi = f32_bf16_rne(w2[(k0 + 2 * j2 + 1) * 128 + n]);
            r[j2] = lo | (hi << 16);
        }
        w2f[i] = r;
    }
    // E1[t][n] = sum_k emb[t][k] * w1[k][n]  (f32 exact; coalesced over n)
    if (tid < 6400) {
        const int t = tid >> 7, n = tid & 127;
        float s = 0.f;
        #pragma unroll 4
        for (int k = 0; k < 128; ++k)
            s = fmaf(emb[t * 128 + k], w1[k * 128 + n], s);
        E1[t * 132 + n] = s;
    }
    if (tid == 0) {                                   // uniform temporal-LN sums
        float Sw = 0.f, Sb = 0.f, Sww = 0.f, Swb = 0.f, Sbb = 0.f;
        for (int j = 0; j < 32; ++j) {
            const float ww = tp_w[j], bb = tp_b[j];
            Sw += ww; Sb += bb; Sww += ww * ww; Swb += ww * bb; Sbb += bb * bb;
        }
        tps[0] = Sw; tps[1] = Sb; tps[2] = Sww; tps[3] = Swb; tps[4] = Sbb;
    }
}

// -------- main: 768 threads = 12 waves; THREE batch rows per block with a
//          FLATTENED tile list (round 11): tiles of all 3 rows form one list
//          of length T; wave w takes t = w, w+12, ... Every wave executes
//          ceil(T/12) +-1 tiles -> intra-block imbalance (the 27% vs 37.5%
//          occupancy gap) eliminated. Per-tile (row, tl) derivation is
//          wave-uniform scalar work. Pools are three NAMED register arrays
//          (rule: runtime-indexed arrays go to scratch) selected by a
//          wave-uniform branch; per-wave partials -> poolbuf[3][12][128].
//
// REGISTER DISCIPLINE (rounds 2-5,7): (768,3) = 170-reg budget; round-10
// measured 68 arch + 64 acc; pools add ~24 -> ~150-160 peak, inside budget.
// Phases strictly serial per tile; coefficients in LDS; empty-asm fences only
// (per-wave DS pipe is in-order).
// SPILL TRIPWIRE: WRITE_SIZE > 50 MB => revert to round-10 layout.
__global__ __launch_bounds__(768, 3) void encoder_mfma(
    const int*   __restrict__ tids,  const float* __restrict__ dates,
    const int*   __restrict__ lengths,
    const float* __restrict__ tp_w,  const float* __restrict__ tp_b,
    const float* __restrict__ tp_lnw,const float* __restrict__ tp_lnb,
    const float* __restrict__ b1,    const float* __restrict__ ln1w, const float* __restrict__ ln1b,
    const float* __restrict__ b2,    const float* __restrict__ ln2w, const float* __restrict__ ln2b,
    const unsigned* __restrict__ ws, float* __restrict__ out,
    int B, int L)
{
    __shared__ __align__(16) uint4v wlds[WLDS_U4];                // 40 KB: w1tf|w2f
    __shared__ __align__(16) float  E1lds[6600];                  // 26.4 KB
    // per-wave C->A transpose scratch (single m-tile): [wave][kt2][row64][j]
    __shared__ __align__(16) unsigned short a2[12][4][64][8];     // 48 KB
    __shared__ float poolbuf[3][12][128];                         // 18 KB
    __shared__ __align__(16) f32x4 tcoef[32];    // {tp_w, tp_b, tp_lnw, tp_lnb}
    __shared__ __align__(16) f32x4 ecoef1[128];  // {b1, ln1w, ln1b, -}
    __shared__ __align__(16) f32x4 ecoef2[128];  // {b2, ln2w, ln2b, -}

    const int tid = threadIdx.x;
    const int lane = tid & 63, w = tid >> 6;          // w in 0..11
    const int c = lane & 15, g = lane >> 4;
    const int b0 = blockIdx.x * 3;

    // ---- stage weights + E1 into LDS ----
    for (int i = tid; i < WLDS_U4; i += 768)
        wlds[i] = ((const uint4v*)ws)[i];
    for (int i = tid; i < E1_U4; i += 768)
        ((uint4v*)E1lds)[i] = ((const uint4v*)ws)[WLDS_U4 + i];

    const float* tps = (const float*)((const uint4v*)ws + WLDS_U4 + E1_U4);

    if (tid < 32)  tcoef[tid]  = (f32x4){tp_w[tid], tp_b[tid], tp_lnw[tid], tp_lnb[tid]};
    if (tid < 128) {
        ecoef1[tid] = (f32x4){b1[tid], ln1w[tid], ln1b[tid], 0.f};
        ecoef2[tid] = (f32x4){b2[tid], ln2w[tid], ln2b[tid], 0.f};
    }
    __syncthreads();

    const float Sw = tps[0], Sb = tps[1], Sww = tps[2], Swb = tps[3], Sbb = tps[4];

    // flattened tile list over the block's 3 rows
    const int len0 = (b0 + 0 < B) ? min(max(lengths[b0 + 0], 0), L) : 0;
    const int len1 = (b0 + 1 < B) ? min(max(lengths[b0 + 1], 0), L) : 0;
    const int len2 = (b0 + 2 < B) ? min(max(lengths[b0 + 2], 0), L) : 0;
    const int nt0 = (len0 + 15) >> 4, nt1 = (len1 + 15) >> 4, nt2 = (len2 + 15) >> 4;
    const int cum1 = nt0, cum2 = nt0 + nt1, T = cum2 + nt2;

    float pool0[8], pool1[8], pool2[8];
    #pragma unroll
    for (int nt = 0; nt < 8; ++nt) { pool0[nt] = 0.f; pool1[nt] = 0.f; pool2[nt] = 0.f; }
    const int srl = lane ^ ((lane >> 3) & 3);          // swizzled GEMM2 read row

    for (int t = w; t < T; t += 12) {
        // wave-uniform (row, local tile) from flattened index
        const int row  = (t >= cum2) ? 2 : ((t >= cum1) ? 1 : 0);
        const int tl   = t - ((row == 2) ? cum2 : ((row == 1) ? cum1 : 0));
        const int bb   = b0 + row;
        const int lenr = (row == 2) ? len2 : ((row == 1) ? len1 : len0);
        const int R0   = tl << 4;
        const long base = (long)bb * L;

        const int pc = min(R0 + c, L - 1);
        const float d = dates[base + pc] * (1.f / 1825.f);
        // ids for this lane's C-layout rows (4g+r); group-uniform broadcast loads
        int idr[4];
        #pragma unroll
        for (int r = 0; r < 4; ++r)
            idr[r] = tids[base + min(R0 + 4 * g + r, L - 1)];

        // temporal A-frag (row = c, k-chunk = g*8..g*8+7); coeffs from LDS
        short8 tfrag;
        {
            const float tm = fmaf(d, Sw, Sb) * (1.f / 32.f);
            float tv = fmaf(d * d, Sww, fmaf(2.f * d, Swb, Sbb)) * (1.f / 32.f) - tm * tm;
            const float trs = rsqrtf(fmaxf(tv, 0.f) + LN_EPS);
            const int j0 = g * 8;
            uint4v r;
            #pragma unroll
            for (int j2 = 0; j2 < 4; ++j2) {
                const f32x4 t0 = tcoef[j0 + 2*j2];
                const f32x4 t1 = tcoef[j0 + 2*j2 + 1];
                const float y0 = fmaf((fmaf(d, t0[0], t0[1]) - tm) * trs, t0[2], t0[3]);
                const float y1 = fmaf((fmaf(d, t1[0], t1[1]) - tm) * trs, t1[2], t1[3]);
                r[j2] = cvt_pk_bf16(gelu_f(y0), gelu_f(y1));
            }
            union { uint4v u; short8 s; } cv; cv.u = r;
            tfrag = cv.s;
        }

        // ---- GEMM1: acc = E1 gather (emb@w1 table) + temporal K=32 MFMA ----
        f32x4 acc[8];
        #pragma unroll
        for (int r = 0; r < 4; ++r) {
            const int e1base = idr[r] * 132 + c;
            #pragma unroll
            for (int nt = 0; nt < 8; ++nt)
                acc[nt][r] = E1lds[e1base + nt * 16];
        }
        __builtin_amdgcn_s_setprio(1);
        #pragma unroll
        for (int nt = 0; nt < 8; ++nt) {
            const short8 bf = ((const short8*)wlds)[nt * 64 + lane];
            acc[nt] = __builtin_amdgcn_mfma_f32_16x16x32_bf16(tfrag, bf, acc[nt], 0, 0, 0);
        }
        __builtin_amdgcn_s_setprio(0);

        // ------- epilogue 1: +b1, LN1 (DPP), GELU -> bf16 a2[w] (swizzled) -------
        {
            f32x4 e1[8];
            #pragma unroll
            for (int nt = 0; nt < 8; ++nt) e1[nt] = ecoef1[nt * 16 + c];
            #pragma unroll
            for (int r = 0; r < 4; ++r) {
                float v[8], s = 0.f, q = 0.f;
                #pragma unroll
                for (int nt = 0; nt < 8; ++nt) {
                    v[nt] = acc[nt][r] + e1[nt][0];
                    s += v[nt]; q = fmaf(v[nt], v[nt], q);
                }
                s = red16(s); q = red16(q);
                const float mean = s * (1.f / 128.f);
                const float var  = fmaxf(q * (1.f / 128.f) - mean * mean, 0.f);
                const float rstd = rsqrtf(var + LN_EPS);
                const int mrow = 4 * g + r;
                #pragma unroll
                for (int n2 = 0; n2 < 4; ++n2) {
                    const float y0 = gelu_f(fmaf((v[2*n2]   - mean) * rstd, e1[2*n2][1],   e1[2*n2][2]));
                    const float y1 = gelu_f(fmaf((v[2*n2+1] - mean) * rstd, e1[2*n2+1][1], e1[2*n2+1][2]));
                    const unsigned pk = cvt_pk_bf16(y0, y1);
                    {
                        const int kcol  = (2*n2) * 16 + c;
                        const int row64 = ((kcol >> 3) & 3) * 16 + mrow;
                        const int srow  = row64 ^ ((row64 >> 3) & 3);
                        a2[w][kcol >> 5][srow][kcol & 7] = (unsigned short)(pk & 0xffffu);
                    }
                    {
                        const int kcol  = (2*n2+1) * 16 + c;
                        const int row64 = ((kcol >> 3) & 3) * 16 + mrow;
                        const int srow  = row64 ^ ((row64 >> 3) & 3);
                        a2[w][kcol >> 5][srow][kcol & 7] = (unsigned short)(pk >> 16);
                    }
                }
            }
        }

        asm volatile("" ::: "memory");                 // order a2 W->R (DS in-order)

        // ---------------- GEMM2: a2[w] @ w2f(LDS) ----------------
        f32x4 acc2[8];
        #pragma unroll
        for (int nt = 0; nt < 8; ++nt) acc2[nt] = (f32x4){0.f, 0.f, 0.f, 0.f};
        __builtin_amdgcn_s_setprio(1);
        #pragma unroll
        for (int kt2 = 0; kt2 < 4; ++kt2) {
            short8 af;
            __builtin_memcpy(&af, &a2[w][kt2][srl][0], 16);
            #pragma unroll
            for (int nt = 0; nt < 8; ++nt) {
                const short8 bf = ((const short8*)(wlds + W1TF_U4))[(kt2 * 8 + nt) * 64 + lane];
                acc2[nt] = __builtin_amdgcn_mfma_f32_16x16x32_bf16(af, bf, acc2[nt], 0, 0, 0);
            }
        }
        __builtin_amdgcn_s_setprio(0);

        asm volatile("" ::: "memory");                 // order a2 R -> next tile W

        // ------- epilogue 2: +b2, LN2, mask -> per-tile pool, then bank it -------
        {
            f32x4 e2[8];
            #pragma unroll
            for (int nt = 0; nt < 8; ++nt) e2[nt] = ecoef2[nt * 16 + c];
            float ptile[8];
            #pragma unroll
            for (int nt = 0; nt < 8; ++nt) ptile[nt] = 0.f;
            #pragma unroll
            for (int r = 0; r < 4; ++r) {
                float v[8], s = 0.f, q = 0.f;
                #pragma unroll
                for (int nt = 0; nt < 8; ++nt) {
                    v[nt] = acc2[nt][r] + e2[nt][0];
                    s += v[nt]; q = fmaf(v[nt], v[nt], q);
                }
                s = red16(s); q = red16(q);
                const float mean = s * (1.f / 128.f);
                const float var  = fmaxf(q * (1.f / 128.f) - mean * mean, 0.f);
                const float rstd = rsqrtf(var + LN_EPS);
                const float msk = ((R0 + 4 * g + r) < lenr) ? 1.f : 0.f;
                #pragma unroll
                for (int nt = 0; nt < 8; ++nt) {
                    const float y = fmaf((v[nt] - mean) * rstd, e2[nt][1], e2[nt][2]);
                    ptile[nt] = fmaf(y, msk, ptile[nt]);
                }
            }
            // bank into the wave-uniform row's named pool (no runtime indexing)
            if (row == 0) {
                #pragma unroll
                for (int nt = 0; nt < 8; ++nt) pool0[nt] += ptile[nt];
            } else if (row == 1) {
                #pragma unroll
                for (int nt = 0; nt < 8; ++nt) pool1[nt] += ptile[nt];
            } else {
                #pragma unroll
                for (int nt = 0; nt < 8; ++nt) pool2[nt] += ptile[nt];
            }
        }
    }

    // wave-level pool reduce (over g groups), then cross-wave combine in LDS
    #pragma unroll
    for (int nt = 0; nt < 8; ++nt) {
        float t0 = pool0[nt]; t0 += __shfl_xor(t0, 16); t0 += __shfl_xor(t0, 32); pool0[nt] = t0;
        float t1 = pool1[nt]; t1 += __shfl_xor(t1, 16); t1 += __shfl_xor(t1, 32); pool1[nt] = t1;
        float t2 = pool2[nt]; t2 += __shfl_xor(t2, 16); t2 += __shfl_xor(t2, 32); pool2[nt] = t2;
    }
    if (g == 0) {
        #pragma unroll
        for (int nt = 0; nt < 8; ++nt) {
            poolbuf[0][w][nt * 16 + c] = pool0[nt];
            poolbuf[1][w][nt * 16 + c] = pool1[nt];
            poolbuf[2][w][nt * 16 + c] = pool2[nt];
        }
    }
    __syncthreads();
    if (tid < 384) {
        const int r3  = tid >> 7;                      // which row of the triple
        const int col = tid & 127;
        const int bo  = b0 + r3;
        if (bo < B) {
            const int lenb = min(max(lengths[bo], 0), L);
            float s = 0.f;
            #pragma unroll
            for (int k = 0; k < 12; ++k) s += poolbuf[r3][k][col];
            out[bo * 128 + col] = (lenb > 0) ? s / (float)lenb : 0.f;
        }
    }
}

extern "C" void kernel_launch(void* const* d_in, const int* in_sizes, int n_in,
                              void* d_out, int out_size, void* d_ws, size_t ws_size,
                              hipStream_t stream) {
    const int*   tids    = (const int*)  d_in[0];
    const float* dates   = (const float*)d_in[1];
    const int*   lengths = (const int*)  d_in[2];
    const float* emb     = (const float*)d_in[3];
    const float* tp_w    = (const float*)d_in[4];
    const float* tp_b    = (const float*)d_in[5];
    const float* tp_lnw  = (const float*)d_in[6];
    const float* tp_lnb  = (const float*)d_in[7];
    const float* w1      = (const float*)d_in[8];
    const float* b1      = (const float*)d_in[9];
    const float* ln1w    = (const float*)d_in[10];
    const float* ln1b    = (const float*)d_in[11];
    const float* w2      = (const float*)d_in[12];
    const float* b2      = (const float*)d_in[13];
    const float* ln2w    = (const float*)d_in[14];
    const float* ln2b    = (const float*)d_in[15];
    float* out = (float*)d_out;

    const int B = in_sizes[2];
    const int L = in_sizes[0] / B;

    hipLaunchKernelGGL(prep_kernel, dim3(32), dim3(256), 0, stream,
                       w1, w2, emb, tp_w, tp_b, (unsigned*)d_ws);
    hipLaunchKernelGGL(encoder_mfma, dim3((B + 2) / 3), dim3(768), 0, stream,
                       tids, dates, lengths, tp_w, tp_b, tp_lnw, tp_lnb,
                       b1, ln1w, ln1b, b2, ln2w, ln2b,
                       (const unsigned*)d_ws, out, B, L);
}